// Round 1
// baseline (162485.583 us; speedup 1.0000x reference)
//
#include <hip/hip_runtime.h>
#include <cstdint>
#include <cstddef>

#define T_STEPS 1024
#define S_DIM   1024
#define A_DIM   64
#define D_DIM   2048
#define H_DIM   2048
#define NWG     256
#define NTHR    256

__device__ __forceinline__ float eluf(float v)      { return v > 0.f ? v : expm1f(v); }
__device__ __forceinline__ float softplusf(float v) { return v > 20.f ? v : log1pf(expf(v)); }
__device__ __forceinline__ float sigmoidf_(float v) { return 1.f / (1.f + expf(-v)); }

__device__ __forceinline__ float wave_reduce(float v) {
  #pragma unroll
  for (int off = 32; off > 0; off >>= 1) v += __shfl_xor(v, off, 64);
  return v;
}

__global__ void init_flags(unsigned* flags) {
  flags[blockIdx.x * blockDim.x + threadIdx.x] = 0u;
}

// All-to-all flag barrier: each WG publishes its own padded flag, every thread
// spins on one flag. Agent-scope release/acquire handles cross-XCD L2.
__device__ __forceinline__ void grid_bar(unsigned* flags, unsigned gen) {
  __threadfence();              // publish this thread's global writes (agent scope)
  __syncthreads();
  if (threadIdx.x == 0)
    __hip_atomic_store(&flags[(size_t)blockIdx.x * 32], gen,
                       __ATOMIC_RELEASE, __HIP_MEMORY_SCOPE_AGENT);
  if (threadIdx.x < NWG) {
    while (__hip_atomic_load(&flags[(size_t)threadIdx.x * 32],
                             __ATOMIC_ACQUIRE, __HIP_MEMORY_SCOPE_AGENT) < gen) {}
  }
  __syncthreads();
}

__global__ __launch_bounds__(NTHR) void rssm_seq(
    const float* __restrict__ pre_act, const float* __restrict__ pre_e,
    float* __restrict__ xbuf, float* __restrict__ qbuf, unsigned* __restrict__ flags,
    const float* __restrict__ p_enc_w,
    const float* __restrict__ gru_wih, const float* __restrict__ gru_whh,
    const float* __restrict__ gru_b, const float* __restrict__ gru_bn,
    const float* __restrict__ q_enc_w,
    const float* __restrict__ q_dec_w, const float* __restrict__ q_dec_b,
    const float* __restrict__ noise,
    float* __restrict__ stoch_out, float* __restrict__ det_out,
    float* __restrict__ qmu_out, float* __restrict__ qstd_out)
{
  const int tid  = threadIdx.x;
  const int wid  = (blockIdx.x * NTHR + tid) >> 6;   // 0..1023
  const int lane = tid & 63;
  unsigned gen = 1;

  for (int t = 0; t < T_STEPS; ++t) {
    const int tp = (t > 0) ? (t - 1) : 0;
    // ---------------- stage 1: x = elu(Wps @ stoch_prev + pre_act[t]) ----------------
    {
      const float* sp = stoch_out + (size_t)tp * S_DIM;
      #pragma unroll
      for (int rr = 0; rr < 2; ++rr) {
        const int r = wid + rr * 1024;
        float acc = 0.f;
        if (t > 0) {
          const float* wrow = p_enc_w + (size_t)r * 1088;
          #pragma unroll
          for (int kc = 0; kc < 4; ++kc) {
            const int k = lane * 4 + kc * 256;
            const float4 w4 = *(const float4*)(wrow + k);
            const float4 s4 = *(const float4*)(sp + k);
            acc += w4.x * s4.x + w4.y * s4.y + w4.z * s4.z + w4.w * s4.w;
          }
        }
        acc = wave_reduce(acc);
        if (lane == 0) xbuf[r] = eluf(acc + pre_act[(size_t)t * D_DIM + r]);
      }
    }
    grid_bar(flags, gen++);
    // ---------------- stage 2: GRU -> det[t] ----------------
    {
      const float* dp = det_out + (size_t)tp * D_DIM;
      #pragma unroll
      for (int rr = 0; rr < 2; ++rr) {
        const int i = wid + rr * 1024;
        const float* wr = gru_wih + (size_t)i * D_DIM;
        const float* wz = gru_wih + (size_t)(i + 2048) * D_DIM;
        const float* wn = gru_wih + (size_t)(i + 4096) * D_DIM;
        const float* ur = gru_whh + (size_t)i * D_DIM;
        const float* uz = gru_whh + (size_t)(i + 2048) * D_DIM;
        const float* un = gru_whh + (size_t)(i + 4096) * D_DIM;
        float ar = 0, az = 0, an = 0, hr = 0, hz = 0, hn = 0;
        #pragma unroll
        for (int kc = 0; kc < 8; ++kc) {
          const int k = lane * 4 + kc * 256;
          const float4 xv = *(const float4*)(xbuf + k);
          float4 w;
          w = *(const float4*)(wr + k); ar += w.x*xv.x + w.y*xv.y + w.z*xv.z + w.w*xv.w;
          w = *(const float4*)(wz + k); az += w.x*xv.x + w.y*xv.y + w.z*xv.z + w.w*xv.w;
          w = *(const float4*)(wn + k); an += w.x*xv.x + w.y*xv.y + w.z*xv.z + w.w*xv.w;
          if (t > 0) {
            const float4 dv = *(const float4*)(dp + k);
            w = *(const float4*)(ur + k); hr += w.x*dv.x + w.y*dv.y + w.z*dv.z + w.w*dv.w;
            w = *(const float4*)(uz + k); hz += w.x*dv.x + w.y*dv.y + w.z*dv.z + w.w*dv.w;
            w = *(const float4*)(un + k); hn += w.x*dv.x + w.y*dv.y + w.z*dv.z + w.w*dv.w;
          }
        }
        ar = wave_reduce(ar); az = wave_reduce(az); an = wave_reduce(an);
        hr = wave_reduce(hr); hz = wave_reduce(hz); hn = wave_reduce(hn);
        if (lane == 0) {
          const float r_ = sigmoidf_(ar + gru_b[i]        + hr);
          const float z_ = sigmoidf_(az + gru_b[i + 2048] + hz);
          const float n_ = tanhf(an + gru_b[i + 4096] + r_ * (hn + gru_bn[i]));
          const float dprev = (t > 0) ? dp[i] : 0.f;
          det_out[(size_t)t * D_DIM + i] = n_ + z_ * (dprev - n_);
        }
      }
    }
    grid_bar(flags, gen++);
    // ---------------- stage 3: q = elu(Wqd @ det + pre_e[t]) ----------------
    {
      const float* det_t = det_out + (size_t)t * D_DIM;
      #pragma unroll
      for (int rr = 0; rr < 2; ++rr) {
        const int r = wid + rr * 1024;
        const float* wrow = q_enc_w + (size_t)r * 4096;   // first 2048 cols
        float acc = 0.f;
        #pragma unroll
        for (int kc = 0; kc < 8; ++kc) {
          const int k = lane * 4 + kc * 256;
          const float4 w4 = *(const float4*)(wrow + k);
          const float4 d4 = *(const float4*)(det_t + k);
          acc += w4.x*d4.x + w4.y*d4.y + w4.z*d4.z + w4.w*d4.w;
        }
        acc = wave_reduce(acc);
        if (lane == 0) qbuf[r] = eluf(acc + pre_e[(size_t)t * H_DIM + r]);
      }
    }
    grid_bar(flags, gen++);
    // ---------------- stage 4: posterior head + sample ----------------
    {
      const int j = wid;   // 0..1023
      const float* wm = q_dec_w + (size_t)j * H_DIM;
      const float* ws2 = q_dec_w + (size_t)(j + 1024) * H_DIM;
      float am = 0, as = 0;
      #pragma unroll
      for (int kc = 0; kc < 8; ++kc) {
        const int k = lane * 4 + kc * 256;
        const float4 qv = *(const float4*)(qbuf + k);
        float4 w;
        w = *(const float4*)(wm + k);  am += w.x*qv.x + w.y*qv.y + w.z*qv.z + w.w*qv.w;
        w = *(const float4*)(ws2 + k); as += w.x*qv.x + w.y*qv.y + w.z*qv.z + w.w*qv.w;
      }
      am = wave_reduce(am); as = wave_reduce(as);
      if (lane == 0) {
        const float qmu = am + q_dec_b[j];
        const float qs  = softplusf(as + q_dec_b[j + 1024]) + 0.1f;
        qmu_out [(size_t)t * S_DIM + j] = qmu;
        qstd_out[(size_t)t * S_DIM + j] = qs;
        stoch_out[(size_t)t * S_DIM + j] = qmu + qs * noise[(size_t)t * S_DIM + j];
      }
    }
    grid_bar(flags, gen++);
  }
}

// C[m,n] = act( sum_k Xc[m,k] * W[n*ldw + woff + k] + bias[n] )
// Xc[m,k] = (k < ksplit) ? X1[m*ldx1+k] : X2[m*ldx2+(k-ksplit)]
// ACT: 0 none, 1 elu, 2 prior-head split (n<1024 -> C(pmu), else softplus+0.1 -> C+1M (pstd))
template <int ACT>
__global__ __launch_bounds__(256) void gemm_xwT(
    const float* __restrict__ X1, int ldx1,
    const float* __restrict__ X2, int ldx2, int ksplit,
    const float* __restrict__ W, int ldw, int woff,
    const float* __restrict__ bias,
    float* __restrict__ C, int ldc,
    int M, int N, int K)
{
  __shared__ float Xs[16][65];
  __shared__ float Ws[16][65];
  const int tid = threadIdx.x;
  const int tx = tid & 15, ty = tid >> 4;
  const int m0 = blockIdx.y * 64, n0 = blockIdx.x * 64;
  const int lrow = tid >> 2;        // 0..63
  const int kq4  = (tid & 3) * 4;   // 0,4,8,12
  float acc[4][4] = {};
  for (int k0 = 0; k0 < K; k0 += 16) {
    {
      const int m = m0 + lrow;
      #pragma unroll
      for (int j = 0; j < 4; ++j) {
        const int k = k0 + kq4 + j;
        float v = 0.f;
        if (m < M)
          v = (k < ksplit) ? X1[(size_t)m * ldx1 + k]
                           : X2[(size_t)m * ldx2 + (k - ksplit)];
        Xs[kq4 + j][lrow] = v;
      }
      const int n = n0 + lrow;
      #pragma unroll
      for (int j = 0; j < 4; ++j) {
        const int k = k0 + kq4 + j;
        Ws[kq4 + j][lrow] = (n < N) ? W[(size_t)n * ldw + woff + k] : 0.f;
      }
    }
    __syncthreads();
    #pragma unroll
    for (int kk = 0; kk < 16; ++kk) {
      float a[4], b[4];
      #pragma unroll
      for (int i = 0; i < 4; ++i) a[i] = Xs[kk][ty * 4 + i];
      #pragma unroll
      for (int j = 0; j < 4; ++j) b[j] = Ws[kk][tx * 4 + j];
      #pragma unroll
      for (int i = 0; i < 4; ++i)
        #pragma unroll
        for (int j = 0; j < 4; ++j)
          acc[i][j] += a[i] * b[j];
    }
    __syncthreads();
  }
  #pragma unroll
  for (int i = 0; i < 4; ++i) {
    const int m = m0 + ty * 4 + i;
    if (m >= M) continue;
    #pragma unroll
    for (int j = 0; j < 4; ++j) {
      const int n = n0 + tx * 4 + j;
      if (n >= N) continue;
      float v = acc[i][j] + bias[n];
      if (ACT == 1) v = eluf(v);
      if (ACT == 2) {
        if (n < 1024) C[(size_t)m * 1024 + n] = v;
        else          C[(size_t)m * 1024 + (n - 1024) + 1024 * 1024] = softplusf(v) + 0.1f;
      } else {
        C[(size_t)m * ldc + n] = v;
      }
    }
  }
}

extern "C" void kernel_launch(void* const* d_in, const int* in_sizes, int n_in,
                              void* d_out, int out_size, void* d_ws, size_t ws_size,
                              hipStream_t stream)
{
  const float* obs      = (const float*)d_in[0];
  const float* acts     = (const float*)d_in[1];
  const float* noise    = (const float*)d_in[2];
  const float* enc_w    = (const float*)d_in[3];
  const float* enc_b    = (const float*)d_in[4];
  const float* dec_w    = (const float*)d_in[5];
  const float* dec_b    = (const float*)d_in[6];
  const float* p_enc_w  = (const float*)d_in[7];
  const float* p_enc_b  = (const float*)d_in[8];
  const float* gru_wih  = (const float*)d_in[9];
  const float* gru_whh  = (const float*)d_in[10];
  const float* gru_b    = (const float*)d_in[11];
  const float* gru_bn   = (const float*)d_in[12];
  const float* p_dec1_w = (const float*)d_in[13];
  const float* p_dec1_b = (const float*)d_in[14];
  const float* p_dec2_w = (const float*)d_in[15];
  const float* p_dec2_b = (const float*)d_in[16];
  const float* q_enc_w  = (const float*)d_in[17];
  const float* q_enc_b  = (const float*)d_in[18];
  const float* q_dec_w  = (const float*)d_in[19];
  const float* q_dec_b  = (const float*)d_in[20];

  float* out   = (float*)d_out;
  float* stoch = out;                     // [1024,1024]
  float* det   = out + 1048576;           // [1024,2048]
  float* outs  = out + 3145728;           // [1024,1026]
  float* qmu   = out + 4196352;           // [1024,1024]
  float* qstd  = out + 5244928;           // [1024,1024]
  float* pmu   = out + 6293504;           // [1024,1024]  (pstd = pmu + 1M, adjacent)

  float* ws       = (float*)d_ws;
  float* pre_act  = ws;                   // [1024,2048]
  float* pre_e    = ws + 2097152;         // [1024,2048]
  float* emb      = ws + 4194304;         // [1024,2048], reused as y after scan
  float* xbuf     = ws + 6291456;         // [2048]
  float* qbuf     = ws + 6293504;         // [2048]
  unsigned* flags = (unsigned*)(ws + 6295552);  // 256*32 u32

  init_flags<<<dim3(32), dim3(256), 0, stream>>>(flags);

  dim3 blk(256);
  // pre_act = act @ p_enc_w[:,1024:].T + p_enc_b
  gemm_xwT<0><<<dim3(32, 16), blk, 0, stream>>>(
      acts, 64, acts, 64, 64, p_enc_w, 1088, 1024, p_enc_b, pre_act, 2048, 1024, 2048, 64);
  // emb = elu(obs @ enc_w.T + enc_b)
  gemm_xwT<1><<<dim3(32, 16), blk, 0, stream>>>(
      obs, 1024, obs, 1024, 1024, enc_w, 1024, 0, enc_b, emb, 2048, 1024, 2048, 1024);
  // pre_e = emb @ q_enc_w[:,2048:].T + q_enc_b
  gemm_xwT<0><<<dim3(32, 16), blk, 0, stream>>>(
      emb, 2048, emb, 2048, 2048, q_enc_w, 4096, 2048, q_enc_b, pre_e, 2048, 1024, 2048, 2048);
  // sequential scan (persistent, 4 grid barriers per step)
  rssm_seq<<<dim3(NWG), dim3(NTHR), 0, stream>>>(
      pre_act, pre_e, xbuf, qbuf, flags,
      p_enc_w, gru_wih, gru_whh, gru_b, gru_bn, q_enc_w, q_dec_w, q_dec_b,
      noise, stoch, det, qmu, qstd);
  // y = elu(det @ p_dec1_w.T + b1)  (into emb region)
  gemm_xwT<1><<<dim3(32, 16), blk, 0, stream>>>(
      det, 2048, det, 2048, 2048, p_dec1_w, 2048, 0, p_dec1_b, emb, 2048, 1024, 2048, 2048);
  // prior head: pmu / pstd = split(y @ p_dec2_w.T + b2), softplus+0.1 on second half
  gemm_xwT<2><<<dim3(32, 16), blk, 0, stream>>>(
      emb, 2048, emb, 2048, 2048, p_dec2_w, 2048, 0, p_dec2_b, pmu, 1024, 1024, 2048, 2048);
  // outs = [stoch|det] @ dec_w.T + dec_b
  gemm_xwT<0><<<dim3(17, 16), blk, 0, stream>>>(
      stoch, 1024, det, 2048, 1024, dec_w, 3072, 0, dec_b, outs, 1026, 1024, 1026, 3072);
}

// Round 2
// 55970.514 us; speedup vs baseline: 2.9031x; 2.9031x over previous
//
#include <hip/hip_runtime.h>
#include <cstdint>
#include <cstddef>

#define T_STEPS 1024
#define S_DIM   1024
#define A_DIM   64
#define D_DIM   2048
#define H_DIM   2048
#define NWG     256
#define NTHR    512   // 8 waves per WG, 1 WG per CU

__device__ __forceinline__ float eluf(float v)      { return v > 0.f ? v : expm1f(v); }
__device__ __forceinline__ float softplusf(float v) { return v > 20.f ? v : log1pf(expf(v)); }
__device__ __forceinline__ float sigmoidf_(float v) { return 1.f / (1.f + expf(-v)); }

__device__ __forceinline__ float wave_reduce(float v) {
  #pragma unroll
  for (int off = 32; off > 0; off >>= 1) v += __shfl_xor(v, off, 64);
  return v;
}

// ---- coherent (cross-XCD) loads/stores: bypass L1+L2, hit the L3 coherence point.
__device__ __forceinline__ float4 ld_coh_f4(const float* p) {
  float4 v;
  asm volatile("global_load_dwordx4 %0, %1, off sc0 sc1\n\ts_waitcnt vmcnt(0)"
               : "=v"(v) : "v"(p) : "memory");
  return v;
}
__device__ __forceinline__ void ld_coh_f4x2(const float* p0, const float* p1,
                                            float4& a, float4& b) {
  asm volatile("global_load_dwordx4 %0, %2, off sc0 sc1\n\t"
               "global_load_dwordx4 %1, %3, off sc0 sc1\n\t"
               "s_waitcnt vmcnt(0)"
               : "=v"(a), "=v"(b) : "v"(p0), "v"(p1) : "memory");
}
__device__ __forceinline__ void st_coh_f1(float* p, float v) {
  asm volatile("global_store_dword %0, %1, off sc0 sc1" :: "v"(p), "v"(v) : "memory");
}

__global__ void init_ctr(unsigned* ctr) { ctr[threadIdx.x] = 0u; }

// Counter barrier with RELAXED atomics only (no buffer_inv / wbl2 storms).
// Data visibility is handled by the sc0/sc1 accesses above.
__device__ __forceinline__ void grid_bar(unsigned* ctr, unsigned target) {
  asm volatile("s_waitcnt vmcnt(0)" ::: "memory");  // this wave's coherent stores done
  __syncthreads();                                   // whole WG's stores done
  if (threadIdx.x == 0) {
    __hip_atomic_fetch_add(ctr, 1u, __ATOMIC_RELAXED, __HIP_MEMORY_SCOPE_AGENT);
    while (__hip_atomic_load(ctr, __ATOMIC_RELAXED, __HIP_MEMORY_SCOPE_AGENT) < target) {}
  }
  __syncthreads();
}

__global__ __launch_bounds__(NTHR) void rssm_seq(
    const float* __restrict__ pre_act, const float* __restrict__ pre_e,
    float* __restrict__ xbuf, float* __restrict__ qbuf, unsigned* __restrict__ ctr,
    const float* __restrict__ p_enc_w,
    const float* __restrict__ gru_wih, const float* __restrict__ gru_whh,
    const float* __restrict__ gru_b, const float* __restrict__ gru_bn,
    const float* __restrict__ q_enc_w,
    const float* __restrict__ q_dec_w, const float* __restrict__ q_dec_b,
    const float* __restrict__ noise,
    float* __restrict__ stoch_out, float* __restrict__ det_out,
    float* __restrict__ qmu_out, float* __restrict__ qstd_out)
{
  __shared__ float sp[1024];   // stoch_prev
  __shared__ float xs[2048];   // x = prior-encoder output
  __shared__ float ds[2048];   // det_prev (stage2) / det_t (stage3)
  __shared__ float qs[2048];   // q vector (stage4)
  __shared__ float part[8];

  const int tid  = threadIdx.x;
  const int wv   = tid >> 6;        // 0..7
  const int lane = tid & 63;
  const int r0   = blockIdx.x * 8;  // this WG's 8 output rows (2048/256)
  unsigned gen = 0;

  for (int t = 0; t < T_STEPS; ++t) {
    // ================= stage 1: x = elu(Wps @ stoch_prev + pre_act[t]) =================
    if (tid < 256) {
      ((float4*)sp)[tid] = (t > 0)
        ? ld_coh_f4(stoch_out + (size_t)(t - 1) * S_DIM + tid * 4)
        : float4{0.f, 0.f, 0.f, 0.f};
    }
    __syncthreads();
    {
      const int r = r0 + wv;
      const float* wrow = p_enc_w + (size_t)r * 1088;
      float acc = 0.f;
      #pragma unroll
      for (int kc = 0; kc < 4; ++kc) {
        const int k = lane * 4 + kc * 256;
        const float4 w4 = *(const float4*)(wrow + k);
        const float4 s4 = *(const float4*)(sp + k);
        acc += w4.x * s4.x + w4.y * s4.y + w4.z * s4.z + w4.w * s4.w;
      }
      acc = wave_reduce(acc);
      if (lane == 0) st_coh_f1(xbuf + r, eluf(acc + pre_act[(size_t)t * D_DIM + r]));
    }
    grid_bar(ctr, ++gen * NWG);

    // ================= stage 2: GRU -> det[t] =================
    if (tid < 512) {
      float4 a, b;
      if (t > 0) {
        ld_coh_f4x2(xbuf + tid * 4, det_out + (size_t)(t - 1) * D_DIM + tid * 4, a, b);
      } else {
        a = ld_coh_f4(xbuf + tid * 4);
        b = float4{0.f, 0.f, 0.f, 0.f};
      }
      ((float4*)xs)[tid] = a;
      ((float4*)ds)[tid] = b;
    }
    __syncthreads();
    {
      const int i = r0 + wv;
      const float* wr = gru_wih + (size_t)i * D_DIM;
      const float* wz = gru_wih + (size_t)(i + 2048) * D_DIM;
      const float* wn = gru_wih + (size_t)(i + 4096) * D_DIM;
      const float* ur = gru_whh + (size_t)i * D_DIM;
      const float* uz = gru_whh + (size_t)(i + 2048) * D_DIM;
      const float* un = gru_whh + (size_t)(i + 4096) * D_DIM;
      float ar = 0, az = 0, an = 0, hr = 0, hz = 0, hn = 0;
      #pragma unroll
      for (int kc = 0; kc < 8; ++kc) {
        const int k = lane * 4 + kc * 256;
        const float4 xv = *(const float4*)(xs + k);
        const float4 dv = *(const float4*)(ds + k);
        float4 w;
        w = *(const float4*)(wr + k); ar += w.x*xv.x + w.y*xv.y + w.z*xv.z + w.w*xv.w;
        w = *(const float4*)(wz + k); az += w.x*xv.x + w.y*xv.y + w.z*xv.z + w.w*xv.w;
        w = *(const float4*)(wn + k); an += w.x*xv.x + w.y*xv.y + w.z*xv.z + w.w*xv.w;
        w = *(const float4*)(ur + k); hr += w.x*dv.x + w.y*dv.y + w.z*dv.z + w.w*dv.w;
        w = *(const float4*)(uz + k); hz += w.x*dv.x + w.y*dv.y + w.z*dv.z + w.w*dv.w;
        w = *(const float4*)(un + k); hn += w.x*dv.x + w.y*dv.y + w.z*dv.z + w.w*dv.w;
      }
      ar = wave_reduce(ar); az = wave_reduce(az); an = wave_reduce(an);
      hr = wave_reduce(hr); hz = wave_reduce(hz); hn = wave_reduce(hn);
      if (lane == 0) {
        const float r_ = sigmoidf_(ar + gru_b[i]        + hr);
        const float z_ = sigmoidf_(az + gru_b[i + 2048] + hz);
        const float n_ = tanhf(an + gru_b[i + 4096] + r_ * (hn + gru_bn[i]));
        const float dprev = ds[i];
        st_coh_f1(det_out + (size_t)t * D_DIM + i, n_ + z_ * (dprev - n_));
      }
    }
    grid_bar(ctr, ++gen * NWG);

    // ================= stage 3: q = elu(Wqd @ det_t + pre_e[t]) =================
    if (tid < 512)
      ((float4*)ds)[tid] = ld_coh_f4(det_out + (size_t)t * D_DIM + tid * 4);
    __syncthreads();
    {
      const int r = r0 + wv;
      const float* wrow = q_enc_w + (size_t)r * 4096;   // first 2048 cols
      float acc = 0.f;
      #pragma unroll
      for (int kc = 0; kc < 8; ++kc) {
        const int k = lane * 4 + kc * 256;
        const float4 w4 = *(const float4*)(wrow + k);
        const float4 d4 = *(const float4*)(ds + k);
        acc += w4.x*d4.x + w4.y*d4.y + w4.z*d4.z + w4.w*d4.w;
      }
      acc = wave_reduce(acc);
      if (lane == 0) st_coh_f1(qbuf + r, eluf(acc + pre_e[(size_t)t * H_DIM + r]));
    }
    grid_bar(ctr, ++gen * NWG);

    // ================= stage 4: posterior head + sample =================
    if (tid < 512)
      ((float4*)qs)[tid] = ld_coh_f4(qbuf + tid * 4);
    __syncthreads();
    {
      // 8 dots per WG: j = j0 + (wv&3), sel = wv>>2 (0 = mu, 1 = std)
      const int j0  = blockIdx.x * 4;
      const int j   = j0 + (wv & 3);
      const int sel = wv >> 2;
      const float* wrow = q_dec_w + (size_t)(j + sel * 1024) * H_DIM;
      float acc = 0.f;
      #pragma unroll
      for (int kc = 0; kc < 8; ++kc) {
        const int k = lane * 4 + kc * 256;
        const float4 w4 = *(const float4*)(wrow + k);
        const float4 q4 = *(const float4*)(qs + k);
        acc += w4.x*q4.x + w4.y*q4.y + w4.z*q4.z + w4.w*q4.w;
      }
      acc = wave_reduce(acc);
      if (lane == 0) part[wv] = acc;
    }
    __syncthreads();
    if (tid < 4) {
      const int j = blockIdx.x * 4 + tid;
      const float qmu = part[tid]     + q_dec_b[j];
      const float qsd = softplusf(part[tid + 4] + q_dec_b[j + 1024]) + 0.1f;
      qmu_out [(size_t)t * S_DIM + j] = qmu;   // harness-only: plain store
      qstd_out[(size_t)t * S_DIM + j] = qsd;
      st_coh_f1(stoch_out + (size_t)t * S_DIM + j,
                qmu + qsd * noise[(size_t)t * S_DIM + j]);
    }
    grid_bar(ctr, ++gen * NWG);
  }
}

// C[m,n] = act( sum_k Xc[m,k] * W[n*ldw + woff + k] + bias[n] )
// Xc[m,k] = (k < ksplit) ? X1[m*ldx1+k] : X2[m*ldx2+(k-ksplit)]
// ACT: 0 none, 1 elu, 2 prior-head split (n<1024 -> C(pmu), else softplus+0.1 -> C+1M (pstd))
template <int ACT>
__global__ __launch_bounds__(256) void gemm_xwT(
    const float* __restrict__ X1, int ldx1,
    const float* __restrict__ X2, int ldx2, int ksplit,
    const float* __restrict__ W, int ldw, int woff,
    const float* __restrict__ bias,
    float* __restrict__ C, int ldc,
    int M, int N, int K)
{
  __shared__ float Xs[16][65];
  __shared__ float Ws[16][65];
  const int tid = threadIdx.x;
  const int tx = tid & 15, ty = tid >> 4;
  const int m0 = blockIdx.y * 64, n0 = blockIdx.x * 64;
  const int lrow = tid >> 2;        // 0..63
  const int kq4  = (tid & 3) * 4;   // 0,4,8,12
  float acc[4][4] = {};
  for (int k0 = 0; k0 < K; k0 += 16) {
    {
      const int m = m0 + lrow;
      #pragma unroll
      for (int j = 0; j < 4; ++j) {
        const int k = k0 + kq4 + j;
        float v = 0.f;
        if (m < M)
          v = (k < ksplit) ? X1[(size_t)m * ldx1 + k]
                           : X2[(size_t)m * ldx2 + (k - ksplit)];
        Xs[kq4 + j][lrow] = v;
      }
      const int n = n0 + lrow;
      #pragma unroll
      for (int j = 0; j < 4; ++j) {
        const int k = k0 + kq4 + j;
        Ws[kq4 + j][lrow] = (n < N) ? W[(size_t)n * ldw + woff + k] : 0.f;
      }
    }
    __syncthreads();
    #pragma unroll
    for (int kk = 0; kk < 16; ++kk) {
      float a[4], b[4];
      #pragma unroll
      for (int i = 0; i < 4; ++i) a[i] = Xs[kk][ty * 4 + i];
      #pragma unroll
      for (int j = 0; j < 4; ++j) b[j] = Ws[kk][tx * 4 + j];
      #pragma unroll
      for (int i = 0; i < 4; ++i)
        #pragma unroll
        for (int j = 0; j < 4; ++j)
          acc[i][j] += a[i] * b[j];
    }
    __syncthreads();
  }
  #pragma unroll
  for (int i = 0; i < 4; ++i) {
    const int m = m0 + ty * 4 + i;
    if (m >= M) continue;
    #pragma unroll
    for (int j = 0; j < 4; ++j) {
      const int n = n0 + tx * 4 + j;
      if (n >= N) continue;
      float v = acc[i][j] + bias[n];
      if (ACT == 1) v = eluf(v);
      if (ACT == 2) {
        if (n < 1024) C[(size_t)m * 1024 + n] = v;
        else          C[(size_t)m * 1024 + (n - 1024) + 1024 * 1024] = softplusf(v) + 0.1f;
      } else {
        C[(size_t)m * ldc + n] = v;
      }
    }
  }
}

extern "C" void kernel_launch(void* const* d_in, const int* in_sizes, int n_in,
                              void* d_out, int out_size, void* d_ws, size_t ws_size,
                              hipStream_t stream)
{
  const float* obs      = (const float*)d_in[0];
  const float* acts     = (const float*)d_in[1];
  const float* noise    = (const float*)d_in[2];
  const float* enc_w    = (const float*)d_in[3];
  const float* enc_b    = (const float*)d_in[4];
  const float* dec_w    = (const float*)d_in[5];
  const float* dec_b    = (const float*)d_in[6];
  const float* p_enc_w  = (const float*)d_in[7];
  const float* p_enc_b  = (const float*)d_in[8];
  const float* gru_wih  = (const float*)d_in[9];
  const float* gru_whh  = (const float*)d_in[10];
  const float* gru_b    = (const float*)d_in[11];
  const float* gru_bn   = (const float*)d_in[12];
  const float* p_dec1_w = (const float*)d_in[13];
  const float* p_dec1_b = (const float*)d_in[14];
  const float* p_dec2_w = (const float*)d_in[15];
  const float* p_dec2_b = (const float*)d_in[16];
  const float* q_enc_w  = (const float*)d_in[17];
  const float* q_enc_b  = (const float*)d_in[18];
  const float* q_dec_w  = (const float*)d_in[19];
  const float* q_dec_b  = (const float*)d_in[20];

  float* out   = (float*)d_out;
  float* stoch = out;                     // [1024,1024]
  float* det   = out + 1048576;           // [1024,2048]
  float* outs  = out + 3145728;           // [1024,1026]
  float* qmu   = out + 4196352;           // [1024,1024]
  float* qstd  = out + 5244928;           // [1024,1024]
  float* pmu   = out + 6293504;           // [1024,1024]  (pstd = pmu + 1M, adjacent)

  float* ws       = (float*)d_ws;
  float* pre_act  = ws;                   // [1024,2048]
  float* pre_e    = ws + 2097152;         // [1024,2048]
  float* emb      = ws + 4194304;         // [1024,2048], reused as y after scan
  float* xbuf     = ws + 6291456;         // [2048]
  float* qbuf     = ws + 6293504;         // [2048]
  unsigned* ctr   = (unsigned*)(ws + 6295552);  // barrier counter

  init_ctr<<<dim3(1), dim3(64), 0, stream>>>(ctr);

  dim3 blk(256);
  // pre_act = act @ p_enc_w[:,1024:].T + p_enc_b
  gemm_xwT<0><<<dim3(32, 16), blk, 0, stream>>>(
      acts, 64, acts, 64, 64, p_enc_w, 1088, 1024, p_enc_b, pre_act, 2048, 1024, 2048, 64);
  // emb = elu(obs @ enc_w.T + enc_b)
  gemm_xwT<1><<<dim3(32, 16), blk, 0, stream>>>(
      obs, 1024, obs, 1024, 1024, enc_w, 1024, 0, enc_b, emb, 2048, 1024, 2048, 1024);
  // pre_e = emb @ q_enc_w[:,2048:].T + q_enc_b
  gemm_xwT<0><<<dim3(32, 16), blk, 0, stream>>>(
      emb, 2048, emb, 2048, 2048, q_enc_w, 4096, 2048, q_enc_b, pre_e, 2048, 1024, 2048, 2048);
  // sequential scan (persistent, 4 grid barriers per step)
  rssm_seq<<<dim3(NWG), dim3(NTHR), 0, stream>>>(
      pre_act, pre_e, xbuf, qbuf, ctr,
      p_enc_w, gru_wih, gru_whh, gru_b, gru_bn, q_enc_w, q_dec_w, q_dec_b,
      noise, stoch, det, qmu, qstd);
  // y = elu(det @ p_dec1_w.T + b1)  (into emb region)
  gemm_xwT<1><<<dim3(32, 16), blk, 0, stream>>>(
      det, 2048, det, 2048, 2048, p_dec1_w, 2048, 0, p_dec1_b, emb, 2048, 1024, 2048, 2048);
  // prior head: pmu / pstd = split(y @ p_dec2_w.T + b2), softplus+0.1 on second half
  gemm_xwT<2><<<dim3(32, 16), blk, 0, stream>>>(
      emb, 2048, emb, 2048, 2048, p_dec2_w, 2048, 0, p_dec2_b, pmu, 1024, 1024, 2048, 2048);
  // outs = [stoch|det] @ dec_w.T + dec_b
  gemm_xwT<0><<<dim3(17, 16), blk, 0, stream>>>(
      stoch, 1024, det, 2048, 1024, dec_w, 3072, 0, dec_b, outs, 1026, 1024, 1026, 3072);
}

// Round 3
// 40760.986 us; speedup vs baseline: 3.9863x; 1.3731x over previous
//
#include <hip/hip_runtime.h>
#include <cstdint>
#include <cstddef>

#define T_STEPS 1024
#define S_DIM   1024
#define A_DIM   64
#define D_DIM   2048
#define H_DIM   2048
#define NWG     256
#define NTHR    512   // 8 waves per WG, 1 WG per CU

typedef unsigned short ushort_t;

__device__ __forceinline__ float eluf(float v)      { return v > 0.f ? v : expm1f(v); }
__device__ __forceinline__ float softplusf(float v) { return v > 20.f ? v : log1pf(expf(v)); }
__device__ __forceinline__ float sigmoidf_(float v) { return 1.f / (1.f + expf(-v)); }

__device__ __forceinline__ float wave_reduce(float v) {
  #pragma unroll
  for (int off = 32; off > 0; off >>= 1) v += __shfl_xor(v, off, 64);
  return v;
}

// unpack a u32 holding two bf16 (e0 = low half, e1 = high half)
__device__ __forceinline__ float2 bf2(unsigned u) {
  float2 r;
  r.x = __uint_as_float(u << 16);
  r.y = __uint_as_float(u & 0xffff0000u);
  return r;
}
__device__ __forceinline__ ushort_t f2bf_rne(float f) {
  unsigned u = __float_as_uint(f);
  u += 0x7fffu + ((u >> 16) & 1u);
  return (ushort_t)(u >> 16);
}

// ---- coherent (cross-XCD) loads/stores: bypass L1+L2, hit the L3 coherence point.
__device__ __forceinline__ float4 ld_coh_f4(const float* p) {
  float4 v;
  asm volatile("global_load_dwordx4 %0, %1, off sc0 sc1\n\ts_waitcnt vmcnt(0)"
               : "=v"(v) : "v"(p) : "memory");
  return v;
}
__device__ __forceinline__ void ld_coh_f4x2(const float* p0, const float* p1,
                                            float4& a, float4& b) {
  asm volatile("global_load_dwordx4 %0, %2, off sc0 sc1\n\t"
               "global_load_dwordx4 %1, %3, off sc0 sc1\n\t"
               "s_waitcnt vmcnt(0)"
               : "=v"(a), "=v"(b) : "v"(p0), "v"(p1) : "memory");
}
__device__ __forceinline__ void st_coh_f1(float* p, float v) {
  asm volatile("global_store_dword %0, %1, off sc0 sc1" :: "v"(p), "v"(v) : "memory");
}

__global__ void init_ctr(unsigned* ctr) { ctr[threadIdx.x] = 0u; }

// pack fp32 matrix (src_ld stride) -> bf16 packed (cols stride); cols is pow2
__global__ __launch_bounds__(256) void pack_bf16(
    const float* __restrict__ src, ushort_t* __restrict__ dst,
    int src_ld, int lc /*log2(cols)*/, size_t total4)
{
  const size_t cmask = ((size_t)1 << lc) - 1;
  for (size_t idx = (size_t)blockIdx.x * blockDim.x + threadIdx.x; idx < total4;
       idx += (size_t)gridDim.x * blockDim.x) {
    const size_t e = idx * 4;
    const size_t r = e >> lc;
    const size_t c = e & cmask;
    const float4 v = *(const float4*)(src + r * src_ld + c);
    ushort_t o[4] = { f2bf_rne(v.x), f2bf_rne(v.y), f2bf_rne(v.z), f2bf_rne(v.w) };
    *(ushort2*)(dst + e)     = *(ushort2*)&o[0];
    *(ushort2*)(dst + e + 2) = *(ushort2*)&o[2];
  }
}

// Counter barrier with RELAXED atomics only (no buffer_inv / wbl2 storms).
__device__ __forceinline__ void grid_bar(unsigned* ctr, unsigned target) {
  asm volatile("s_waitcnt vmcnt(0)" ::: "memory");
  __syncthreads();
  if (threadIdx.x == 0) {
    __hip_atomic_fetch_add(ctr, 1u, __ATOMIC_RELAXED, __HIP_MEMORY_SCOPE_AGENT);
    while (__hip_atomic_load(ctr, __ATOMIC_RELAXED, __HIP_MEMORY_SCOPE_AGENT) < target) {}
  }
  __syncthreads();
}

template <typename WT> struct WTr;
template <> struct WTr<float>    { static constexpr int CH = 4; };
template <> struct WTr<ushort_t> { static constexpr int CH = 8; };

// dot( weight row, vector in LDS ), row length N, lane-partitioned
template <typename WT, int N>
__device__ __forceinline__ float row_dot(const WT* __restrict__ wrow,
                                         const float* __restrict__ v, int lane) {
  constexpr int CH = WTr<WT>::CH;
  constexpr int NJ = N / (64 * CH);
  float acc = 0.f;
  #pragma unroll
  for (int j = 0; j < NJ; ++j) {
    const int k = lane * CH + j * 64 * CH;
    if constexpr (CH == 4) {
      const float4 w = *(const float4*)(wrow + k);
      const float4 a = *(const float4*)(v + k);
      acc += w.x*a.x + w.y*a.y + w.z*a.z + w.w*a.w;
    } else {
      const uint4 w = *(const uint4*)(wrow + k);
      const float4 a0 = *(const float4*)(v + k);
      const float4 a1 = *(const float4*)(v + k + 4);
      float2 p;
      p = bf2(w.x); acc += p.x*a0.x + p.y*a0.y;
      p = bf2(w.y); acc += p.x*a0.z + p.y*a0.w;
      p = bf2(w.z); acc += p.x*a1.x + p.y*a1.y;
      p = bf2(w.w); acc += p.x*a1.z + p.y*a1.w;
    }
  }
  return acc;
}

// dot( weight row, lane-resident register slice ar[32] ), row length 2048
template <typename WT>
__device__ __forceinline__ float row_dot_reg(const WT* __restrict__ wrow,
                                             const float* __restrict__ ar, int lane) {
  constexpr int CH = WTr<WT>::CH;
  constexpr int NJ = 2048 / (64 * CH);
  float acc = 0.f;
  #pragma unroll
  for (int j = 0; j < NJ; ++j) {
    const int k = lane * CH + j * 64 * CH;
    if constexpr (CH == 4) {
      const float4 w = *(const float4*)(wrow + k);
      acc += w.x*ar[j*4+0] + w.y*ar[j*4+1] + w.z*ar[j*4+2] + w.w*ar[j*4+3];
    } else {
      const uint4 w = *(const uint4*)(wrow + k);
      float2 p;
      p = bf2(w.x); acc += p.x*ar[j*8+0] + p.y*ar[j*8+1];
      p = bf2(w.y); acc += p.x*ar[j*8+2] + p.y*ar[j*8+3];
      p = bf2(w.z); acc += p.x*ar[j*8+4] + p.y*ar[j*8+5];
      p = bf2(w.w); acc += p.x*ar[j*8+6] + p.y*ar[j*8+7];
    }
  }
  return acc;
}

template <typename WT>
__global__ __launch_bounds__(NTHR) void rssm_seq(
    const float* __restrict__ pre_act, const float* __restrict__ pre_e,
    float* __restrict__ xbuf, float* __restrict__ qbuf, unsigned* __restrict__ ctr,
    const WT* __restrict__ wps, int wps_ld,
    const WT* __restrict__ wih, const WT* __restrict__ whh,
    const float* __restrict__ gru_b, const float* __restrict__ gru_bn,
    const WT* __restrict__ wqe, int wqe_ld,
    const WT* __restrict__ wqd,
    const float* __restrict__ q_dec_b, const float* __restrict__ noise,
    float* __restrict__ stoch_out, float* __restrict__ det_out,
    float* __restrict__ qmu_out, float* __restrict__ qstd_out)
{
  __shared__ float sp[1024];   // stoch_prev
  __shared__ float xs[2048];   // x = prior-encoder output
  __shared__ float ds[2048];   // det_prev (stage2) / det_t (stage3)
  __shared__ float qs[2048];   // q vector (stage4)
  __shared__ float part[8];

  constexpr int CH  = WTr<WT>::CH;
  constexpr int NJ2 = 2048 / (64 * CH);

  const int tid  = threadIdx.x;
  const int wv   = tid >> 6;        // 0..7
  const int lane = tid & 63;
  const int r0   = blockIdx.x * 8;  // this WG's 8 rows of 2048
  unsigned gen = 0;

  for (int t = 0; t < T_STEPS; ++t) {
    // ================= stage 1: x = elu(Wps @ stoch_prev + pre_act[t]) =================
    if (tid < 256) {
      ((float4*)sp)[tid] = (t > 0)
        ? ld_coh_f4(stoch_out + (size_t)(t - 1) * S_DIM + tid * 4)
        : float4{0.f, 0.f, 0.f, 0.f};
    }
    __syncthreads();
    {
      const int r = r0 + wv;
      const float acc = wave_reduce(row_dot<WT, 1024>(wps + (size_t)r * wps_ld, sp, lane));
      if (lane == 0) st_coh_f1(xbuf + r, eluf(acc + pre_act[(size_t)t * D_DIM + r]));
    }
    grid_bar(ctr, ++gen * NWG);

    // ================= stage 2: GRU -> det[t] =================
    if (tid < 512) {
      float4 a, b;
      if (t > 0) {
        ld_coh_f4x2(xbuf + tid * 4, det_out + (size_t)(t - 1) * D_DIM + tid * 4, a, b);
      } else {
        a = ld_coh_f4(xbuf + tid * 4);
        b = float4{0.f, 0.f, 0.f, 0.f};
      }
      ((float4*)xs)[tid] = a;
      ((float4*)ds)[tid] = b;
    }
    __syncthreads();
    {
      // lane-resident slices of x and det_prev, reused across all 6 gate rows
      float xr[32], dr[32];
      #pragma unroll
      for (int j = 0; j < NJ2; ++j) {
        const int k = lane * CH + j * 64 * CH;
        #pragma unroll
        for (int i = 0; i < CH; ++i) { xr[j*CH+i] = xs[k+i]; dr[j*CH+i] = ds[k+i]; }
      }
      const int i = r0 + wv;
      float ar = row_dot_reg<WT>(wih + (size_t)i          * 2048, xr, lane);
      float az = row_dot_reg<WT>(wih + (size_t)(i + 2048) * 2048, xr, lane);
      float an = row_dot_reg<WT>(wih + (size_t)(i + 4096) * 2048, xr, lane);
      float hr = row_dot_reg<WT>(whh + (size_t)i          * 2048, dr, lane);
      float hz = row_dot_reg<WT>(whh + (size_t)(i + 2048) * 2048, dr, lane);
      float hn = row_dot_reg<WT>(whh + (size_t)(i + 4096) * 2048, dr, lane);
      ar = wave_reduce(ar); az = wave_reduce(az); an = wave_reduce(an);
      hr = wave_reduce(hr); hz = wave_reduce(hz); hn = wave_reduce(hn);
      if (lane == 0) {
        const float r_ = sigmoidf_(ar + gru_b[i]        + hr);
        const float z_ = sigmoidf_(az + gru_b[i + 2048] + hz);
        const float n_ = tanhf(an + gru_b[i + 4096] + r_ * (hn + gru_bn[i]));
        const float dprev = ds[i];
        st_coh_f1(det_out + (size_t)t * D_DIM + i, n_ + z_ * (dprev - n_));
      }
    }
    grid_bar(ctr, ++gen * NWG);

    // ================= stage 3: q = elu(Wqe @ det_t + pre_e[t]) =================
    if (tid < 512)
      ((float4*)ds)[tid] = ld_coh_f4(det_out + (size_t)t * D_DIM + tid * 4);
    __syncthreads();
    {
      const int r = r0 + wv;
      const float acc = wave_reduce(row_dot<WT, 2048>(wqe + (size_t)r * wqe_ld, ds, lane));
      if (lane == 0) st_coh_f1(qbuf + r, eluf(acc + pre_e[(size_t)t * H_DIM + r]));
    }
    grid_bar(ctr, ++gen * NWG);

    // ================= stage 4: posterior head + sample =================
    if (tid < 512)
      ((float4*)qs)[tid] = ld_coh_f4(qbuf + tid * 4);
    __syncthreads();
    {
      const int j   = blockIdx.x * 4 + (wv & 3);
      const int sel = wv >> 2;
      const float acc =
          wave_reduce(row_dot<WT, 2048>(wqd + (size_t)(j + sel * 1024) * 2048, qs, lane));
      if (lane == 0) part[wv] = acc;
    }
    __syncthreads();
    if (tid < 4) {
      const int j = blockIdx.x * 4 + tid;
      const float qmu = part[tid]     + q_dec_b[j];
      const float qsd = softplusf(part[tid + 4] + q_dec_b[j + 1024]) + 0.1f;
      qmu_out [(size_t)t * S_DIM + j] = qmu;
      qstd_out[(size_t)t * S_DIM + j] = qsd;
      st_coh_f1(stoch_out + (size_t)t * S_DIM + j,
                qmu + qsd * noise[(size_t)t * S_DIM + j]);
    }
    grid_bar(ctr, ++gen * NWG);
  }
}

// C[m,n] = act( sum_k Xc[m,k] * W[n*ldw + woff + k] + bias[n] )
template <int ACT>
__global__ __launch_bounds__(256) void gemm_xwT(
    const float* __restrict__ X1, int ldx1,
    const float* __restrict__ X2, int ldx2, int ksplit,
    const float* __restrict__ W, int ldw, int woff,
    const float* __restrict__ bias,
    float* __restrict__ C, int ldc,
    int M, int N, int K)
{
  __shared__ float Xs[16][65];
  __shared__ float Ws[16][65];
  const int tid = threadIdx.x;
  const int tx = tid & 15, ty = tid >> 4;
  const int m0 = blockIdx.y * 64, n0 = blockIdx.x * 64;
  const int lrow = tid >> 2;
  const int kq4  = (tid & 3) * 4;
  float acc[4][4] = {};
  for (int k0 = 0; k0 < K; k0 += 16) {
    {
      const int m = m0 + lrow;
      #pragma unroll
      for (int j = 0; j < 4; ++j) {
        const int k = k0 + kq4 + j;
        float v = 0.f;
        if (m < M)
          v = (k < ksplit) ? X1[(size_t)m * ldx1 + k]
                           : X2[(size_t)m * ldx2 + (k - ksplit)];
        Xs[kq4 + j][lrow] = v;
      }
      const int n = n0 + lrow;
      #pragma unroll
      for (int j = 0; j < 4; ++j) {
        const int k = k0 + kq4 + j;
        Ws[kq4 + j][lrow] = (n < N) ? W[(size_t)n * ldw + woff + k] : 0.f;
      }
    }
    __syncthreads();
    #pragma unroll
    for (int kk = 0; kk < 16; ++kk) {
      float a[4], b[4];
      #pragma unroll
      for (int i = 0; i < 4; ++i) a[i] = Xs[kk][ty * 4 + i];
      #pragma unroll
      for (int j = 0; j < 4; ++j) b[j] = Ws[kk][tx * 4 + j];
      #pragma unroll
      for (int i = 0; i < 4; ++i)
        #pragma unroll
        for (int j = 0; j < 4; ++j)
          acc[i][j] += a[i] * b[j];
    }
    __syncthreads();
  }
  #pragma unroll
  for (int i = 0; i < 4; ++i) {
    const int m = m0 + ty * 4 + i;
    if (m >= M) continue;
    #pragma unroll
    for (int j = 0; j < 4; ++j) {
      const int n = n0 + tx * 4 + j;
      if (n >= N) continue;
      float v = acc[i][j] + bias[n];
      if (ACT == 1) v = eluf(v);
      if (ACT == 2) {
        if (n < 1024) C[(size_t)m * 1024 + n] = v;
        else          C[(size_t)m * 1024 + (n - 1024) + 1024 * 1024] = softplusf(v) + 0.1f;
      } else {
        C[(size_t)m * ldc + n] = v;
      }
    }
  }
}

extern "C" void kernel_launch(void* const* d_in, const int* in_sizes, int n_in,
                              void* d_out, int out_size, void* d_ws, size_t ws_size,
                              hipStream_t stream)
{
  const float* obs      = (const float*)d_in[0];
  const float* acts     = (const float*)d_in[1];
  const float* noise    = (const float*)d_in[2];
  const float* enc_w    = (const float*)d_in[3];
  const float* enc_b    = (const float*)d_in[4];
  const float* dec_w    = (const float*)d_in[5];
  const float* dec_b    = (const float*)d_in[6];
  const float* p_enc_w  = (const float*)d_in[7];
  const float* p_enc_b  = (const float*)d_in[8];
  const float* gru_wih  = (const float*)d_in[9];
  const float* gru_whh  = (const float*)d_in[10];
  const float* gru_b    = (const float*)d_in[11];
  const float* gru_bn   = (const float*)d_in[12];
  const float* p_dec1_w = (const float*)d_in[13];
  const float* p_dec1_b = (const float*)d_in[14];
  const float* p_dec2_w = (const float*)d_in[15];
  const float* p_dec2_b = (const float*)d_in[16];
  const float* q_enc_w  = (const float*)d_in[17];
  const float* q_enc_b  = (const float*)d_in[18];
  const float* q_dec_w  = (const float*)d_in[19];
  const float* q_dec_b  = (const float*)d_in[20];

  float* out   = (float*)d_out;
  float* stoch = out;                     // [1024,1024]
  float* det   = out + 1048576;           // [1024,2048]
  float* outs  = out + 3145728;           // [1024,1026]
  float* qmu   = out + 4196352;           // [1024,1024]
  float* qstd  = out + 5244928;           // [1024,1024]
  float* pmu   = out + 6293504;           // [1024,1024] (pstd adjacent)

  float* ws       = (float*)d_ws;
  float* pre_act  = ws;                          // 2,097,152 f
  float* pre_e    = ws + 2097152;                // 2,097,152 f
  float* emb      = ws + 4194304;                // 2,097,152 f
  float* xbuf     = ws + 6291456;                // 2048 f
  float* qbuf     = ws + 6293504;                // 2048 f
  unsigned* ctr   = (unsigned*)(ws + 6295552);   // pad to 4096 f
  ushort_t* wpack = (ushort_t*)(ws + 6299648);
  ushort_t* wps_h = wpack;                       //  2,097,152 us
  ushort_t* wih_h = wps_h + 2097152;             // 12,582,912 us
  ushort_t* whh_h = wih_h + 12582912;            // 12,582,912 us
  ushort_t* wqe_h = whh_h + 12582912;            //  4,194,304 us
  ushort_t* wqd_h = wqe_h + 4194304;             //  4,194,304 us
  const size_t need = 6299648ull * 4 + 35651584ull * 2;   // ~96.5 MB
  const bool use_bf16 = ws_size >= need;

  init_ctr<<<dim3(1), dim3(64), 0, stream>>>(ctr);

  if (use_bf16) {
    pack_bf16<<<dim3(2048), dim3(256), 0, stream>>>(p_enc_w, wps_h, 1088, 10, 524288);
    pack_bf16<<<dim3(2048), dim3(256), 0, stream>>>(gru_wih, wih_h, 2048, 11, 3145728);
    pack_bf16<<<dim3(2048), dim3(256), 0, stream>>>(gru_whh, whh_h, 2048, 11, 3145728);
    pack_bf16<<<dim3(2048), dim3(256), 0, stream>>>(q_enc_w, wqe_h, 4096, 11, 1048576);
    pack_bf16<<<dim3(2048), dim3(256), 0, stream>>>(q_dec_w, wqd_h, 2048, 11, 1048576);
  }

  dim3 blk(256);
  gemm_xwT<0><<<dim3(32, 16), blk, 0, stream>>>(
      acts, 64, acts, 64, 64, p_enc_w, 1088, 1024, p_enc_b, pre_act, 2048, 1024, 2048, 64);
  gemm_xwT<1><<<dim3(32, 16), blk, 0, stream>>>(
      obs, 1024, obs, 1024, 1024, enc_w, 1024, 0, enc_b, emb, 2048, 1024, 2048, 1024);
  gemm_xwT<0><<<dim3(32, 16), blk, 0, stream>>>(
      emb, 2048, emb, 2048, 2048, q_enc_w, 4096, 2048, q_enc_b, pre_e, 2048, 1024, 2048, 2048);

  if (use_bf16) {
    rssm_seq<ushort_t><<<dim3(NWG), dim3(NTHR), 0, stream>>>(
        pre_act, pre_e, xbuf, qbuf, ctr,
        wps_h, 1024, wih_h, whh_h, gru_b, gru_bn, wqe_h, 2048, wqd_h,
        q_dec_b, noise, stoch, det, qmu, qstd);
  } else {
    rssm_seq<float><<<dim3(NWG), dim3(NTHR), 0, stream>>>(
        pre_act, pre_e, xbuf, qbuf, ctr,
        p_enc_w, 1088, gru_wih, gru_whh, gru_b, gru_bn, q_enc_w, 4096, q_dec_w,
        q_dec_b, noise, stoch, det, qmu, qstd);
  }

  gemm_xwT<1><<<dim3(32, 16), blk, 0, stream>>>(
      det, 2048, det, 2048, 2048, p_dec1_w, 2048, 0, p_dec1_b, emb, 2048, 1024, 2048, 2048);
  gemm_xwT<2><<<dim3(32, 16), blk, 0, stream>>>(
      emb, 2048, emb, 2048, 2048, p_dec2_w, 2048, 0, p_dec2_b, pmu, 1024, 1024, 2048, 2048);
  gemm_xwT<0><<<dim3(17, 16), blk, 0, stream>>>(
      stoch, 1024, det, 2048, 1024, dec_w, 3072, 0, dec_b, outs, 1026, 1024, 1026, 3072);
}

// Round 4
// 29362.338 us; speedup vs baseline: 5.5338x; 1.3882x over previous
//
#include <hip/hip_runtime.h>
#include <cstdint>
#include <cstddef>

#define T_STEPS 1024
#define S_DIM   1024
#define A_DIM   64
#define D_DIM   2048
#define H_DIM   2048
#define NWG     256
#define NTHR    1024   // 16 waves per WG, 1 WG per CU

typedef unsigned short ushort_t;

__device__ __forceinline__ float eluf(float v)      { return v > 0.f ? v : expm1f(v); }
__device__ __forceinline__ float softplusf(float v) { return v > 20.f ? v : log1pf(expf(v)); }
__device__ __forceinline__ float sigmoidf_(float v) { return 1.f / (1.f + expf(-v)); }

__device__ __forceinline__ float wave_reduce(float v) {
  #pragma unroll
  for (int off = 32; off > 0; off >>= 1) v += __shfl_xor(v, off, 64);
  return v;
}

// unpack a u32 holding two bf16 (e0 = low half, e1 = high half)
__device__ __forceinline__ float2 bf2(unsigned u) {
  float2 r;
  r.x = __uint_as_float(u << 16);
  r.y = __uint_as_float(u & 0xffff0000u);
  return r;
}
__device__ __forceinline__ ushort_t f2bf_rne(float f) {
  unsigned u = __float_as_uint(f);
  u += 0x7fffu + ((u >> 16) & 1u);
  return (ushort_t)(u >> 16);
}

// ---- coherent (cross-XCD) accesses: bypass L1/L2, hit the coherence point.
__device__ __forceinline__ float4 ld_coh_f4(const float* p) {
  float4 v;
  asm volatile("global_load_dwordx4 %0, %1, off sc0 sc1\n\ts_waitcnt vmcnt(0)"
               : "=v"(v) : "v"(p) : "memory");
  return v;
}
// store + completion fence (used in epilogues so grid_bar needn't drain vmcnt)
__device__ __forceinline__ void st_coh_f1_fence(float* p, float v) {
  asm volatile("global_store_dword %0, %1, off sc0 sc1\n\ts_waitcnt vmcnt(0)"
               :: "v"(p), "v"(v) : "memory");
}

__global__ void init_flags(unsigned* f) { f[blockIdx.x * blockDim.x + threadIdx.x] = 0u; }

// Flag-array grid barrier: parallel stores to 256 padded lines; wave 0 polls.
__device__ __forceinline__ void grid_bar(unsigned* myflag, unsigned gen, int tid,
                                         const unsigned* pf0, const unsigned* pf1,
                                         const unsigned* pf2, const unsigned* pf3) {
  __syncthreads();   // all waves' epilogue stores already fenced
  if (tid == 0)
    asm volatile("global_store_dword %0, %1, off sc0 sc1"
                 :: "v"(myflag), "v"(gen) : "memory");
  if (tid < 64) {
    bool done;
    do {
      unsigned a, b, c, d;
      asm volatile("global_load_dword %0, %4, off sc0 sc1\n\t"
                   "global_load_dword %1, %5, off sc0 sc1\n\t"
                   "global_load_dword %2, %6, off sc0 sc1\n\t"
                   "global_load_dword %3, %7, off sc0 sc1\n\t"
                   "s_waitcnt vmcnt(0)"
                   : "=v"(a), "=v"(b), "=v"(c), "=v"(d)
                   : "v"(pf0), "v"(pf1), "v"(pf2), "v"(pf3) : "memory");
      done = (a >= gen) && (b >= gen) && (c >= gen) && (d >= gen);
    } while (!__all(done));
  }
  __syncthreads();
}

// fp32 -> bf16 pack with per-512-chunk column swizzle:
// dst pos (within row): chunk*512 + l*8 + p*2 + e  <-  src k: chunk*512 + p*128 + l*2 + e
// so a lane's uint4 (8 bf16) pairs with float2 LDS reads at stride 8B (bank-friendly).
__global__ __launch_bounds__(256) void pack_swz(
    const float* __restrict__ src, unsigned* __restrict__ dst,
    int src_ld, int lc /*log2 cols*/, size_t total2 /*u32 count*/)
{
  for (size_t u = (size_t)blockIdx.x * 256 + threadIdx.x; u < total2;
       u += (size_t)gridDim.x * 256) {
    const size_t pos = u * 2;
    const size_t row = pos >> lc;
    const int pcol  = (int)(pos & (((size_t)1 << lc) - 1));
    const int chunk = pcol >> 9;
    const int off   = pcol & 511;
    const int l     = off >> 3;
    const int p     = (off >> 1) & 3;
    const float2 v  = *(const float2*)(src + row * src_ld + chunk * 512 + p * 128 + l * 2);
    dst[u] = (unsigned)f2bf_rne(v.x) | ((unsigned)f2bf_rne(v.y) << 16);
  }
}

// dot of one swizzled 512-chunk (uint4 = 8 bf16) against LDS chunk
__device__ __forceinline__ float chunk_dot(const uint4 w, const float* vchunk, int lane) {
  float acc = 0.f; float2 p, a;
  a = *(const float2*)(vchunk + lane * 2 +   0); p = bf2(w.x); acc += p.x*a.x + p.y*a.y;
  a = *(const float2*)(vchunk + lane * 2 + 128); p = bf2(w.y); acc += p.x*a.x + p.y*a.y;
  a = *(const float2*)(vchunk + lane * 2 + 256); p = bf2(w.z); acc += p.x*a.x + p.y*a.y;
  a = *(const float2*)(vchunk + lane * 2 + 384); p = bf2(w.w); acc += p.x*a.x + p.y*a.y;
  return acc;
}

__global__ __launch_bounds__(NTHR) void rssm_seq(
    const float* __restrict__ pre_act, const float* __restrict__ pre_e,
    float* __restrict__ xbuf, float* __restrict__ qbuf, unsigned* __restrict__ flags,
    const ushort_t* __restrict__ wps,
    const ushort_t* __restrict__ wih, const ushort_t* __restrict__ whh,
    const float* __restrict__ gru_b, const float* __restrict__ gru_bn,
    const ushort_t* __restrict__ wqe, const ushort_t* __restrict__ wqd,
    const float* __restrict__ q_dec_b, const float* __restrict__ noise,
    float* __restrict__ stoch_out, float* __restrict__ det_out,
    float* __restrict__ qmu_out, float* __restrict__ qstd_out)
{
  __shared__ float sp[1024];      // stoch_prev
  __shared__ float xs[2048];      // x vector
  __shared__ float ds[2048];      // det_prev (stage1/2) then det_t (stage3)
  __shared__ float qs[2048];      // q vector
  __shared__ float partg[8][6];   // GRU gate partials
  __shared__ float part3[8][2];
  __shared__ float part4[8][2];

  const int tid  = threadIdx.x;
  const int wv   = tid >> 6;          // 0..15
  const int lane = tid & 63;
  const int bid  = blockIdx.x;
  const int r0   = bid * 8;           // 8 rows of 2048 per WG
  unsigned* myflag = flags + (size_t)bid * 16;
  const unsigned* pf0 = flags + (size_t)tid * 16;            // valid for tid<64
  const unsigned* pf1 = flags + (size_t)(tid + 64)  * 16;
  const unsigned* pf2 = flags + (size_t)(tid + 128) * 16;
  const unsigned* pf3 = flags + (size_t)(tid + 192) * 16;
  unsigned gen = 0;

  // prefetch stage-1 weights (waves 0..7: row r0+wv, full K=1024 = 2 chunks)
  uint4 pw1a = {}, pw1b = {};
  if (wv < 8) {
    const uint4* wr = (const uint4*)(wps + (size_t)(r0 + wv) * 1024);
    pw1a = wr[lane];
    pw1b = wr[64 + lane];
  }

  for (int t = 0; t < T_STEPS; ++t) {
    // ---- staging: sp (stoch_prev) by tids<256, ds (det_prev) by tids>=512 ----
    if (tid < 256) {
      ((float4*)sp)[tid] = (t > 0)
        ? ld_coh_f4(stoch_out + (size_t)(t - 1) * S_DIM + tid * 4)
        : float4{0.f, 0.f, 0.f, 0.f};
    } else if (tid >= 512) {
      const int i2 = tid - 512;
      ((float4*)ds)[i2] = (t > 0)
        ? ld_coh_f4(det_out + (size_t)(t - 1) * D_DIM + i2 * 4)
        : float4{0.f, 0.f, 0.f, 0.f};
    }
    __syncthreads();

    // ================= stage 1: x = elu(Wps @ stoch_prev + pre_act[t]) =================
    if (wv < 8) {
      float acc = chunk_dot(pw1a, sp, lane) + chunk_dot(pw1b, sp + 512, lane);
      acc = wave_reduce(acc);
      if (lane == 0)
        st_coh_f1_fence(xbuf + r0 + wv, eluf(acc + pre_act[(size_t)t * D_DIM + r0 + wv]));
    }

    // prefetch stage-2 weights: wave<8 -> (ar,az,an) of row r0+wv vs x;
    //                           wave>=8 -> (hr,hz,hn) of row r0+wv-8 vs det_prev
    uint4 pw2[12];
    {
      const int row = wv & 7;
      const ushort_t* wbase = (wv < 8) ? wih : whh;
      const size_t i = (size_t)(r0 + row);
      #pragma unroll
      for (int g = 0; g < 3; ++g) {
        const uint4* wr = (const uint4*)(wbase + (i + (size_t)g * 2048) * 2048);
        #pragma unroll
        for (int j = 0; j < 4; ++j) pw2[g * 4 + j] = wr[j * 64 + lane];
      }
    }
    grid_bar(myflag, ++gen, tid, pf0, pf1, pf2, pf3);

    // ================= stage 2: GRU -> det[t] =================
    if (tid < 512) ((float4*)xs)[tid] = ld_coh_f4(xbuf + tid * 4);
    __syncthreads();
    {
      const float* vec = (wv < 8) ? xs : ds;
      float a0 = 0.f, a1 = 0.f, a2 = 0.f;
      #pragma unroll
      for (int j = 0; j < 4; ++j) {
        const float* b = vec + j * 512 + lane * 2;
        const float2 v0 = *(const float2*)(b);
        const float2 v1 = *(const float2*)(b + 128);
        const float2 v2 = *(const float2*)(b + 256);
        const float2 v3 = *(const float2*)(b + 384);
        float2 p; uint4 w;
        w = pw2[j];
        p = bf2(w.x); a0 += p.x*v0.x + p.y*v0.y;
        p = bf2(w.y); a0 += p.x*v1.x + p.y*v1.y;
        p = bf2(w.z); a0 += p.x*v2.x + p.y*v2.y;
        p = bf2(w.w); a0 += p.x*v3.x + p.y*v3.y;
        w = pw2[4 + j];
        p = bf2(w.x); a1 += p.x*v0.x + p.y*v0.y;
        p = bf2(w.y); a1 += p.x*v1.x + p.y*v1.y;
        p = bf2(w.z); a1 += p.x*v2.x + p.y*v2.y;
        p = bf2(w.w); a1 += p.x*v3.x + p.y*v3.y;
        w = pw2[8 + j];
        p = bf2(w.x); a2 += p.x*v0.x + p.y*v0.y;
        p = bf2(w.y); a2 += p.x*v1.x + p.y*v1.y;
        p = bf2(w.z); a2 += p.x*v2.x + p.y*v2.y;
        p = bf2(w.w); a2 += p.x*v3.x + p.y*v3.y;
      }
      a0 = wave_reduce(a0); a1 = wave_reduce(a1); a2 = wave_reduce(a2);
      if (lane == 0) {
        const int row = wv & 7;
        if (wv < 8) { partg[row][0] = a0; partg[row][1] = a1; partg[row][2] = a2; }
        else        { partg[row][3] = a0; partg[row][4] = a1; partg[row][5] = a2; }
      }
    }
    __syncthreads();
    if (tid < 8) {
      const int i = r0 + tid;
      const float r_ = sigmoidf_(partg[tid][0] + gru_b[i]        + partg[tid][3]);
      const float z_ = sigmoidf_(partg[tid][1] + gru_b[i + 2048] + partg[tid][4]);
      const float n_ = tanhf(partg[tid][2] + gru_b[i + 4096] + r_ * (partg[tid][5] + gru_bn[i]));
      st_coh_f1_fence(det_out + (size_t)t * D_DIM + i, n_ + z_ * (ds[i] - n_));
    }

    // prefetch stage-3 weights: wave = (row, khalf)
    uint4 pw3[2];
    {
      const int row = wv & 7, half = wv >> 3;
      const uint4* wr = (const uint4*)(wqe + (size_t)(r0 + row) * 2048);
      pw3[0] = wr[(2 * half)     * 64 + lane];
      pw3[1] = wr[(2 * half + 1) * 64 + lane];
    }
    grid_bar(myflag, ++gen, tid, pf0, pf1, pf2, pf3);

    // ================= stage 3: q = elu(Wqe @ det_t + pre_e[t]) =================
    if (tid < 512) ((float4*)ds)[tid] = ld_coh_f4(det_out + (size_t)t * D_DIM + tid * 4);
    __syncthreads();
    {
      const int row = wv & 7, half = wv >> 3;
      float acc = chunk_dot(pw3[0], ds + (2 * half) * 512, lane)
                + chunk_dot(pw3[1], ds + (2 * half + 1) * 512, lane);
      acc = wave_reduce(acc);
      if (lane == 0) part3[row][half] = acc;
    }
    __syncthreads();
    if (tid < 8) {
      const int r = r0 + tid;
      st_coh_f1_fence(qbuf + r,
                      eluf(part3[tid][0] + part3[tid][1] + pre_e[(size_t)t * H_DIM + r]));
    }

    // prefetch stage-4 weights: wave = (dot 0..7, khalf)
    uint4 pw4[2];
    {
      const int dot = wv >> 1, half = wv & 1;
      const int jg = bid * 4 + (dot & 3), sel = dot >> 2;
      const uint4* wr = (const uint4*)(wqd + (size_t)(jg + sel * 1024) * 2048);
      pw4[0] = wr[(2 * half)     * 64 + lane];
      pw4[1] = wr[(2 * half + 1) * 64 + lane];
    }
    grid_bar(myflag, ++gen, tid, pf0, pf1, pf2, pf3);

    // ================= stage 4: posterior head + sample =================
    if (tid < 512) ((float4*)qs)[tid] = ld_coh_f4(qbuf + tid * 4);
    __syncthreads();
    {
      const int dot = wv >> 1, half = wv & 1;
      float acc = chunk_dot(pw4[0], qs + (2 * half) * 512, lane)
                + chunk_dot(pw4[1], qs + (2 * half + 1) * 512, lane);
      acc = wave_reduce(acc);
      if (lane == 0) part4[dot][half] = acc;
    }
    __syncthreads();
    if (tid < 4) {
      const int j = bid * 4 + tid;
      const float qm  = part4[tid][0] + part4[tid][1] + q_dec_b[j];
      const float qsd = softplusf(part4[tid + 4][0] + part4[tid + 4][1] + q_dec_b[j + 1024]) + 0.1f;
      qmu_out [(size_t)t * S_DIM + j] = qm;
      qstd_out[(size_t)t * S_DIM + j] = qsd;
      st_coh_f1_fence(stoch_out + (size_t)t * S_DIM + j,
                      qm + qsd * noise[(size_t)t * S_DIM + j]);
    }

    // prefetch stage-1 weights for next step (same addresses -> L1/L2 hits)
    if (wv < 8) {
      const uint4* wr = (const uint4*)(wps + (size_t)(r0 + wv) * 1024);
      pw1a = wr[lane];
      pw1b = wr[64 + lane];
    }
    grid_bar(myflag, ++gen, tid, pf0, pf1, pf2, pf3);
  }
}

// C[m,n] = act( sum_k Xc[m,k] * W[n*ldw + woff + k] + bias[n] )
template <int ACT>
__global__ __launch_bounds__(256) void gemm_xwT(
    const float* __restrict__ X1, int ldx1,
    const float* __restrict__ X2, int ldx2, int ksplit,
    const float* __restrict__ W, int ldw, int woff,
    const float* __restrict__ bias,
    float* __restrict__ C, int ldc,
    int M, int N, int K)
{
  __shared__ float Xs[16][65];
  __shared__ float Ws[16][65];
  const int tid = threadIdx.x;
  const int tx = tid & 15, ty = tid >> 4;
  const int m0 = blockIdx.y * 64, n0 = blockIdx.x * 64;
  const int lrow = tid >> 2;
  const int kq4  = (tid & 3) * 4;
  float acc[4][4] = {};
  for (int k0 = 0; k0 < K; k0 += 16) {
    {
      const int m = m0 + lrow;
      #pragma unroll
      for (int j = 0; j < 4; ++j) {
        const int k = k0 + kq4 + j;
        float v = 0.f;
        if (m < M)
          v = (k < ksplit) ? X1[(size_t)m * ldx1 + k]
                           : X2[(size_t)m * ldx2 + (k - ksplit)];
        Xs[kq4 + j][lrow] = v;
      }
      const int n = n0 + lrow;
      #pragma unroll
      for (int j = 0; j < 4; ++j) {
        const int k = k0 + kq4 + j;
        Ws[kq4 + j][lrow] = (n < N) ? W[(size_t)n * ldw + woff + k] : 0.f;
      }
    }
    __syncthreads();
    #pragma unroll
    for (int kk = 0; kk < 16; ++kk) {
      float a[4], b[4];
      #pragma unroll
      for (int i = 0; i < 4; ++i) a[i] = Xs[kk][ty * 4 + i];
      #pragma unroll
      for (int j = 0; j < 4; ++j) b[j] = Ws[kk][tx * 4 + j];
      #pragma unroll
      for (int i = 0; i < 4; ++i)
        #pragma unroll
        for (int j = 0; j < 4; ++j)
          acc[i][j] += a[i] * b[j];
    }
    __syncthreads();
  }
  #pragma unroll
  for (int i = 0; i < 4; ++i) {
    const int m = m0 + ty * 4 + i;
    if (m >= M) continue;
    #pragma unroll
    for (int j = 0; j < 4; ++j) {
      const int n = n0 + tx * 4 + j;
      if (n >= N) continue;
      float v = acc[i][j] + bias[n];
      if (ACT == 1) v = eluf(v);
      if (ACT == 2) {
        if (n < 1024) C[(size_t)m * 1024 + n] = v;
        else          C[(size_t)m * 1024 + (n - 1024) + 1024 * 1024] = softplusf(v) + 0.1f;
      } else {
        C[(size_t)m * ldc + n] = v;
      }
    }
  }
}

extern "C" void kernel_launch(void* const* d_in, const int* in_sizes, int n_in,
                              void* d_out, int out_size, void* d_ws, size_t ws_size,
                              hipStream_t stream)
{
  const float* obs      = (const float*)d_in[0];
  const float* acts     = (const float*)d_in[1];
  const float* noise    = (const float*)d_in[2];
  const float* enc_w    = (const float*)d_in[3];
  const float* enc_b    = (const float*)d_in[4];
  const float* dec_w    = (const float*)d_in[5];
  const float* dec_b    = (const float*)d_in[6];
  const float* p_enc_w  = (const float*)d_in[7];
  const float* p_enc_b  = (const float*)d_in[8];
  const float* gru_wih  = (const float*)d_in[9];
  const float* gru_whh  = (const float*)d_in[10];
  const float* gru_b    = (const float*)d_in[11];
  const float* gru_bn   = (const float*)d_in[12];
  const float* p_dec1_w = (const float*)d_in[13];
  const float* p_dec1_b = (const float*)d_in[14];
  const float* p_dec2_w = (const float*)d_in[15];
  const float* p_dec2_b = (const float*)d_in[16];
  const float* q_enc_w  = (const float*)d_in[17];
  const float* q_enc_b  = (const float*)d_in[18];
  const float* q_dec_w  = (const float*)d_in[19];
  const float* q_dec_b  = (const float*)d_in[20];

  float* out   = (float*)d_out;
  float* stoch = out;                     // [1024,1024]
  float* det   = out + 1048576;           // [1024,2048]
  float* outs  = out + 3145728;           // [1024,1026]
  float* qmu   = out + 4196352;           // [1024,1024]
  float* qstd  = out + 5244928;           // [1024,1024]
  float* pmu   = out + 6293504;           // [1024,1024] (pstd adjacent)

  float* ws       = (float*)d_ws;
  float* pre_act  = ws;                          // 2,097,152 f
  float* pre_e    = ws + 2097152;                // 2,097,152 f
  float* emb      = ws + 4194304;                // 2,097,152 f
  float* xbuf     = ws + 6291456;                // 2048 f
  float* qbuf     = ws + 6293504;                // 2048 f
  unsigned* flags = (unsigned*)(ws + 6295552);   // 4096 u32 (256 x 64B)
  ushort_t* wpack = (ushort_t*)(ws + 6299648);
  ushort_t* wps_h = wpack;                       //  2,097,152 us
  ushort_t* wih_h = wps_h + 2097152;             // 12,582,912 us
  ushort_t* whh_h = wih_h + 12582912;            // 12,582,912 us
  ushort_t* wqe_h = whh_h + 12582912;            //  4,194,304 us
  ushort_t* wqd_h = wqe_h + 4194304;             //  4,194,304 us

  init_flags<<<dim3(16), dim3(256), 0, stream>>>(flags);

  // bf16 pack with chunk swizzle
  pack_swz<<<dim3(1024), dim3(256), 0, stream>>>(p_enc_w, (unsigned*)wps_h, 1088, 10, 1048576);
  pack_swz<<<dim3(1024), dim3(256), 0, stream>>>(gru_wih, (unsigned*)wih_h, 2048, 11, 6291456);
  pack_swz<<<dim3(1024), dim3(256), 0, stream>>>(gru_whh, (unsigned*)whh_h, 2048, 11, 6291456);
  pack_swz<<<dim3(1024), dim3(256), 0, stream>>>(q_enc_w, (unsigned*)wqe_h, 4096, 11, 2097152);
  pack_swz<<<dim3(1024), dim3(256), 0, stream>>>(q_dec_w, (unsigned*)wqd_h, 2048, 11, 2097152);

  dim3 blk(256);
  gemm_xwT<0><<<dim3(32, 16), blk, 0, stream>>>(
      acts, 64, acts, 64, 64, p_enc_w, 1088, 1024, p_enc_b, pre_act, 2048, 1024, 2048, 64);
  gemm_xwT<1><<<dim3(32, 16), blk, 0, stream>>>(
      obs, 1024, obs, 1024, 1024, enc_w, 1024, 0, enc_b, emb, 2048, 1024, 2048, 1024);
  gemm_xwT<0><<<dim3(32, 16), blk, 0, stream>>>(
      emb, 2048, emb, 2048, 2048, q_enc_w, 4096, 2048, q_enc_b, pre_e, 2048, 1024, 2048, 2048);

  rssm_seq<<<dim3(NWG), dim3(NTHR), 0, stream>>>(
      pre_act, pre_e, xbuf, qbuf, flags,
      wps_h, wih_h, whh_h, gru_b, gru_bn, wqe_h, wqd_h,
      q_dec_b, noise, stoch, det, qmu, qstd);

  gemm_xwT<1><<<dim3(32, 16), blk, 0, stream>>>(
      det, 2048, det, 2048, 2048, p_dec1_w, 2048, 0, p_dec1_b, emb, 2048, 1024, 2048, 2048);
  gemm_xwT<2><<<dim3(32, 16), blk, 0, stream>>>(
      emb, 2048, emb, 2048, 2048, p_dec2_w, 2048, 0, p_dec2_b, pmu, 1024, 1024, 2048, 2048);
  gemm_xwT<0><<<dim3(17, 16), blk, 0, stream>>>(
      stoch, 1024, det, 2048, 1024, dec_w, 3072, 0, dec_b, outs, 1026, 1024, 1026, 3072);
}